// Round 6
// baseline (316.090 us; speedup 1.0000x reference)
//
#include <hip/hip_runtime.h>
#include <hip/hip_bf16.h>

typedef short short8 __attribute__((ext_vector_type(8)));
typedef float f32x4 __attribute__((ext_vector_type(4)));

// LDS arena 81920 B -> 2 blocks/CU.
// [0,64K):  XN bf16 xn^T [w][c]                     (P2->P3)
//           then AT fp8 A[w][v] [0,16K) + XS fp8 x[c][v] [16K,48K)   (post-P3 -> P4)
//           then YT bf16 Y^T [w][c] full 64K         (post-P4 -> P5)
//           then FLD bf16 F packed [0,64K)           (post-P5 -> epilogue)
// [64K,72K) GB (P3 G-band) || overlay NW/NB/UU/MUO/RSO/UDO (P0-P2, dead before GB writes)
// [72K,80K) SUMO/SQO stat partials (P1-P2 only)
#define XN 0
#define AT 0
#define XS 16384
#define YT 0
#define FLD 0
#define GB 65536
#define NW 65536
#define NB 66560
#define UU 67584
#define MUO 68608
#define RSO 69120
#define UDO 69632
#define SUMO 73728
#define SQO 77824
#define LDS_BYTES 81920

__device__ inline unsigned short cvtbf(float f){
  unsigned int x = __float_as_uint(f);
  x += 0x7fffu + ((x >> 16) & 1u);           // RNE
  return (unsigned short)(x >> 16);
}
__device__ inline float bf2f(unsigned short u){ return __uint_as_float(((unsigned int)u) << 16); }
// packed f32x2 -> bf16x2, proven manual RNE (R1-R4; inline-asm cvt_pk NaN'd in R5)
__device__ inline unsigned int pk2(float a, float b){
  return (unsigned int)cvtbf(a) | ((unsigned int)cvtbf(b) << 16);
}
__device__ inline float lo16(unsigned int v){ return bf2f((unsigned short)(v & 0xffffu)); }
__device__ inline float hi16(unsigned int v){ return bf2f((unsigned short)(v >> 16)); }

// setup: M = wq^T wk (bf16), wv -> bf16, u = wk^T bq. 64 blocks x 4 rows each.
__global__ void __launch_bounds__(256) setup_kernel(
    const float* __restrict__ wq, const float* __restrict__ bq,
    const float* __restrict__ wk, const float* __restrict__ wvw,
    unsigned short* __restrict__ Mbf, unsigned short* __restrict__ wvbf, float* __restrict__ u){
  int t = threadIdx.x;
  int c1b = blockIdx.x * 4;
  float acc[4] = {0.f,0.f,0.f,0.f};
  for (int o = 0; o < 256; ++o){
    float wkv = wk[o*256 + t];
    #pragma unroll
    for (int i = 0; i < 4; ++i) acc[i] = fmaf(wq[o*256 + c1b + i], wkv, acc[i]);
  }
  #pragma unroll
  for (int i = 0; i < 4; ++i){
    Mbf[(c1b+i)*256 + t] = cvtbf(acc[i]);
    wvbf[(c1b+i)*256 + t] = cvtbf(wvw[(c1b+i)*256 + t]);
  }
  if (blockIdx.x == 0){
    float a2 = 0.f;
    for (int o = 0; o < 256; ++o) a2 = fmaf(wk[o*256 + t], bq[o], a2);
    u[t] = a2;
  }
}

__global__ void __launch_bounds__(512, 4) fused_kernel(
    const float* __restrict__ x, const float* __restrict__ nw, const float* __restrict__ nbp,
    const float* __restrict__ bvv, const float* __restrict__ beta,
    const unsigned short* __restrict__ Mbf, const unsigned short* __restrict__ wvbf,
    const float* __restrict__ u, float* __restrict__ out){
  extern __shared__ char smem[];
  const int t = threadIdx.x;
  const int lane = t & 63, wv8 = t >> 6;      // 8 waves
  const int g = lane >> 4, li = lane & 15;
  const int b = blockIdx.x >> 7, h = blockIdx.x & 127;
  const size_t base = (size_t)b*4194304 + (size_t)h*128;  // x[b,c,h,w] = base + c*16384 + w

  // ---- P0: stage norm params into LDS (GB-overlay region, dead before P3's GB writes)
  if (t < 256){
    ((float*)(smem + NW))[t] = nw[t];
    ((float*)(smem + NB))[t] = nbp[t];
    ((float*)(smem + UU))[t] = u[t];
  }

  // ---- P1: coalesced float2 x loads (512B/wave), per-w stats; keep x bf16-packed in xp
  const int w2 = t & 63, s = t >> 6;          // thread owns c in [s*32,s*32+32), w in {2w2,2w2+1}
  unsigned int xp[32];                         // xp[j] = packed bf16 (x[s*32+j][2w2], x[..][2w2+1])
  {
    const float* xw = x + base + (size_t)(s*32)*16384 + 2*w2;
    float sm0 = 0.f, sq0 = 0.f, sm1 = 0.f, sq1 = 0.f;
    #pragma unroll
    for (int j = 0; j < 32; ++j){
      float2 v = *(const float2*)(xw + (size_t)j*16384);
      sm0 += v.x; sq0 = fmaf(v.x, v.x, sq0);
      sm1 += v.y; sq1 = fmaf(v.y, v.y, sq1);
      xp[j] = pk2(v.x, v.y);
    }
    ((float*)(smem + SUMO))[s*128 + 2*w2]     = sm0;
    ((float*)(smem + SUMO))[s*128 + 2*w2 + 1] = sm1;
    ((float*)(smem + SQO))[s*128 + 2*w2]      = sq0;
    ((float*)(smem + SQO))[s*128 + 2*w2 + 1]  = sq1;
  }
  __syncthreads();
  if (t < 128){
    float sm = 0.f, sq = 0.f;
    #pragma unroll
    for (int q = 0; q < 8; ++q){ sm += ((float*)(smem+SUMO))[q*128+t]; sq += ((float*)(smem+SQO))[q*128+t]; }
    float mu = sm * (1.f/256.f);
    float var = sq * (1.f/256.f) - mu*mu;
    ((float*)(smem+MUO))[t] = mu;
    ((float*)(smem+RSO))[t] = rsqrtf(var + 1e-6f);
  }
  __syncthreads();

  // ---- P2: xn^T [w][c] from registers (2 w-rows per thread); udot partials
  {
    float ud[2] = {0.f, 0.f};
    #pragma unroll
    for (int r = 0; r < 2; ++r){
      int w = 2*w2 + r;
      float mu = ((float*)(smem+MUO))[w], rs = ((float*)(smem+RSO))[w];
      #pragma unroll
      for (int i = 0; i < 4; ++i){
        int c0 = s*32 + i*8;
        unsigned int uu[4];
        #pragma unroll
        for (int j = 0; j < 4; ++j){
          int c = c0 + j*2;
          unsigned int pa = xp[i*8 + j*2];
          unsigned int pb = xp[i*8 + j*2 + 1];
          float x0 = bf2f((unsigned short)(r ? (pa >> 16) : (pa & 0xffffu)));
          float x1 = bf2f((unsigned short)(r ? (pb >> 16) : (pb & 0xffffu)));
          float n0 = (x0 - mu)*rs*((float*)(smem+NW))[c]   + ((float*)(smem+NB))[c];
          float n1 = (x1 - mu)*rs*((float*)(smem+NW))[c+1] + ((float*)(smem+NB))[c+1];
          ud[r] = fmaf(((float*)(smem+UU))[c], n0, fmaf(((float*)(smem+UU))[c+1], n1, ud[r]));
          uu[j] = pk2(n0, n1);
        }
        *(uint4*)(smem + XN + w*512 + ((2*c0) ^ ((w&31)<<4))) = *(const uint4*)uu;
      }
    }
    __syncthreads();   // stat reads of SUMO done; safe to overwrite with ud partials
    ((float*)(smem+SUMO))[s*128 + 2*w2]     = ud[0];
    ((float*)(smem+SUMO))[s*128 + 2*w2 + 1] = ud[1];
  }
  __syncthreads();
  if (t < 128){
    float ud = 0.f;
    #pragma unroll
    for (int q = 0; q < 8; ++q) ud += ((float*)(smem+SUMO))[q*128+t];
    ((float*)(smem+UDO))[t] = ud;
  }
  __syncthreads();

  // ---- P3: S^T[v][w] = sum_o G[o][v]*xn[o][w] (+udot[v]), G in 32-row bands
  f32x4 Sacc[8];
  #pragma unroll
  for (int vt = 0; vt < 8; ++vt){
    int vb = vt*16 + g*4;
    #pragma unroll
    for (int r = 0; r < 4; ++r) Sacc[vt][r] = ((float*)(smem+UDO))[vb + r];
  }
  const int ot = wv8 >> 2, vp = wv8 & 3;
  const int wt = wv8;
  #pragma unroll
  for (int k8 = 0; k8 < 8; ++k8){
    // G band: this wave computes 16 o' x 32 v
    f32x4 Ga[2] = {{0.f,0.f,0.f,0.f},{0.f,0.f,0.f,0.f}};
    const int o = k8*32 + ot*16 + li;
    __builtin_amdgcn_s_setprio(1);
    #pragma unroll
    for (int kk = 0; kk < 8; ++kk){
      short8 afr = *(const short8*)(Mbf + o*256 + kk*32 + g*8);
      #pragma unroll
      for (int j = 0; j < 2; ++j){
        int v = (vp*2 + j)*16 + li;
        short8 bfr = *(const short8*)(smem + XN + v*512 + ((2*(kk*32 + g*8)) ^ ((v&31)<<4)));
        Ga[j] = __builtin_amdgcn_mfma_f32_16x16x32_bf16(afr, bfr, Ga[j], 0, 0, 0);
      }
    }
    __builtin_amdgcn_s_setprio(0);
    __syncthreads();  // prev band's S reads of GB complete
    #pragma unroll
    for (int j = 0; j < 2; ++j){
      int v = (vp*2 + j)*16 + li;
      int ob = ot*16 + g*4;
      uint2 p; p.x = pk2(Ga[j][0], Ga[j][1]); p.y = pk2(Ga[j][2], Ga[j][3]);
      *(uint2*)(smem + GB + v*64 + ((2*ob) ^ ((v&3)<<4))) = p;
    }
    __syncthreads();
    {
      int ww = wt*16 + li;
      short8 bfr = *(const short8*)(smem + XN + ww*512 + ((2*(k8*32 + g*8)) ^ ((ww&31)<<4)));
      __builtin_amdgcn_s_setprio(1);
      #pragma unroll
      for (int vt = 0; vt < 8; ++vt){
        int v = vt*16 + li;
        short8 afr = *(const short8*)(smem + GB + v*64 + ((16*g) ^ ((v&3)<<4)));
        Sacc[vt] = __builtin_amdgcn_mfma_f32_16x16x32_bf16(afr, bfr, Sacc[vt], 0, 0, 0);
      }
      __builtin_amdgcn_s_setprio(0);
    }
  }
  __syncthreads();   // XN fully dead

  // ---- XS: x -> fp8 [c][v] from xp registers (32KB at [16K,48K))
  #pragma unroll
  for (int j = 0; j < 32; ++j){
    int c = s*32 + j;
    int pr = __builtin_amdgcn_cvt_pk_fp8_f32(lo16(xp[j]), hi16(xp[j]), 0, false);
    *(unsigned short*)(smem + XS + c*128 + ((2*w2) ^ ((c&15)<<3))) = (unsigned short)pr;
  }

  // ---- softmax over v (rows of S^T), write A as fp8 [w][v] (16KB at [0,16K))
  float mx = -3.4e38f;
  #pragma unroll
  for (int vt = 0; vt < 8; ++vt)
    #pragma unroll
    for (int r = 0; r < 4; ++r){ float sv = Sacc[vt][r]*0.0625f; Sacc[vt][r] = sv; mx = fmaxf(mx, sv); }
  mx = fmaxf(mx, __shfl_xor(mx, 16));
  mx = fmaxf(mx, __shfl_xor(mx, 32));
  float sum = 0.f;
  #pragma unroll
  for (int vt = 0; vt < 8; ++vt)
    #pragma unroll
    for (int r = 0; r < 4; ++r){ float p = exp2f((Sacc[vt][r]-mx)*1.44269504f); Sacc[vt][r] = p; sum += p; }
  sum += __shfl_xor(sum, 16);
  sum += __shfl_xor(sum, 32);
  float inv = 1.f / sum;
  {
    int ww = wt*16 + li;
    #pragma unroll
    for (int vt = 0; vt < 8; ++vt){
      int pr = __builtin_amdgcn_cvt_pk_fp8_f32(Sacc[vt][0]*inv, Sacc[vt][1]*inv, 0, false);
      pr = __builtin_amdgcn_cvt_pk_fp8_f32(Sacc[vt][2]*inv, Sacc[vt][3]*inv, pr, true);
      *(unsigned int*)(smem + AT + ww*128 + ((vt*16 + g*4) ^ ((ww&15)<<3))) = (unsigned int)pr;
    }
  }
  __syncthreads();

  // ---- P4: Y[c][w] = sum_v x[c][v] A[w][v], all-fp8 MFMA from LDS
  f32x4 Yacc[2][8];
  #pragma unroll
  for (int ci = 0; ci < 2; ++ci)
    #pragma unroll
    for (int w2i = 0; w2i < 8; ++w2i) Yacc[ci][w2i] = (f32x4){0.f,0.f,0.f,0.f};
  #pragma unroll
  for (int kk = 0; kk < 4; ++kk){
    long af[2];
    #pragma unroll
    for (int ci = 0; ci < 2; ++ci){
      int c = (wv8*2 + ci)*16 + li;
      af[ci] = *(const long*)(smem + XS + c*128 + ((kk*32 + g*8) ^ ((c&15)<<3)));
    }
    __builtin_amdgcn_s_setprio(1);
    #pragma unroll
    for (int w2i = 0; w2i < 8; ++w2i){
      int ww = w2i*16 + li;
      long bf = *(const long*)(smem + AT + ww*128 + ((kk*32 + g*8) ^ ((ww&15)<<3)));
      #pragma unroll
      for (int ci = 0; ci < 2; ++ci)
        Yacc[ci][w2i] = __builtin_amdgcn_mfma_f32_16x16x32_fp8_fp8(af[ci], bf, Yacc[ci][w2i], 0, 0, 0);
    }
    __builtin_amdgcn_s_setprio(0);
  }
  __syncthreads();   // all P4 reads of XS/AT done; [0,64K) free for YT

  // ---- Y write: full Y^T bf16 [w][c] (64KB); Yacc dies here, before Facc is born
  #pragma unroll
  for (int ci = 0; ci < 2; ++ci){
    int cb = (wv8*2 + ci)*16 + g*4;
    #pragma unroll
    for (int w2i = 0; w2i < 8; ++w2i){
      int ww = w2i*16 + li;
      uint2 p; p.x = pk2(Yacc[ci][w2i][0], Yacc[ci][w2i][1]); p.y = pk2(Yacc[ci][w2i][2], Yacc[ci][w2i][3]);
      *(uint2*)(smem + YT + ww*512 + ((2*cb) ^ ((ww&31)<<4))) = p;
    }
  }
  __syncthreads();

  // ---- P5: F[o][w] = sum_c wv[o][c] Y[c][w], single full-K phase (wv from global/L2)
  f32x4 Facc[2][8];
  #pragma unroll
  for (int oi = 0; oi < 2; ++oi)
    #pragma unroll
    for (int w2i = 0; w2i < 8; ++w2i) Facc[oi][w2i] = (f32x4){0.f,0.f,0.f,0.f};
  #pragma unroll
  for (int kk = 0; kk < 8; ++kk){
    short8 afr[2];
    #pragma unroll
    for (int oi = 0; oi < 2; ++oi){
      int o = (wv8*2 + oi)*16 + li;
      afr[oi] = *(const short8*)(wvbf + o*256 + kk*32 + g*8);
    }
    __builtin_amdgcn_s_setprio(1);
    #pragma unroll
    for (int w2i = 0; w2i < 8; ++w2i){
      int ww = w2i*16 + li;
      short8 bfr = *(const short8*)(smem + YT + ww*512 + ((2*(kk*32 + g*8)) ^ ((ww&31)<<4)));
      #pragma unroll
      for (int oi = 0; oi < 2; ++oi)
        Facc[oi][w2i] = __builtin_amdgcn_mfma_f32_16x16x32_bf16(afr[oi], bfr, Facc[oi][w2i], 0, 0, 0);
    }
    __builtin_amdgcn_s_setprio(0);
  }
  __syncthreads();   // YT dead; [0,64K) free for FLD

  // ---- FLD: Ffin = (F+bv)*beta as bf16, packed (o-pair, w); bv/beta from global (L2-hot)
  #pragma unroll
  for (int oi = 0; oi < 2; ++oi){
    #pragma unroll
    for (int rp = 0; rp < 2; ++rp){
      int o0 = (wv8*2 + oi)*16 + g*4 + 2*rp;   // even o
      int orow = o0 >> 1;
      float2 bv2 = *(const float2*)(bvv + o0);
      float2 bt2 = *(const float2*)(beta + o0);
      #pragma unroll
      for (int w2i = 0; w2i < 8; ++w2i){
        int w = w2i*16 + li;
        float f0 = (Facc[oi][w2i][2*rp]   + bv2.x)*bt2.x;
        float f1 = (Facc[oi][w2i][2*rp+1] + bv2.y)*bt2.y;
        *(unsigned int*)(smem + FLD + orow*512 + ((4*w) ^ ((orow&7)<<4))) = pk2(f0, f1);
      }
    }
  }
  __syncthreads();

  // ---- epilogue: out = x(from xp) + Ffin; fully coalesced float2 stores, no x re-read
  #pragma unroll
  for (int j = 0; j < 16; ++j){
    int crow = s*16 + j;                        // = (s*32+2j)>>1
    uint2 u2 = *(const uint2*)(smem + FLD + crow*512 + ((8*w2) ^ ((crow&7)<<4)));
    float2 o0, o1;
    o0.x = lo16(xp[2*j])   + lo16(u2.x);
    o0.y = hi16(xp[2*j])   + lo16(u2.y);
    o1.x = lo16(xp[2*j+1]) + hi16(u2.x);
    o1.y = hi16(xp[2*j+1]) + hi16(u2.y);
    size_t c0 = (size_t)(s*32 + 2*j);
    *(float2*)(out + base + c0*16384 + 2*w2)       = o0;
    *(float2*)(out + base + (c0+1)*16384 + 2*w2)   = o1;
  }
}

extern "C" void kernel_launch(void* const* d_in, const int* in_sizes, int n_in,
                              void* d_out, int out_size, void* d_ws, size_t ws_size,
                              hipStream_t stream) {
  (void)in_sizes; (void)n_in; (void)out_size; (void)ws_size;
  const float* x      = (const float*)d_in[0];
  const float* norm_w = (const float*)d_in[1];
  const float* norm_b = (const float*)d_in[2];
  const float* wq     = (const float*)d_in[3];
  const float* bq     = (const float*)d_in[4];
  const float* wk     = (const float*)d_in[5];
  // d_in[6] = bk: only enters softmax-invariant terms, mathematically dropped
  const float* wvw    = (const float*)d_in[7];
  const float* bvv    = (const float*)d_in[8];
  const float* beta   = (const float*)d_in[9];
  float* out = (float*)d_out;

  unsigned short* Mbf  = (unsigned short*)d_ws;                    // 128 KB
  unsigned short* wvbf = (unsigned short*)((char*)d_ws + 131072);  // 128 KB
  float* u             = (float*)((char*)d_ws + 262144);           // 1 KB

  static bool attr_set = false;
  if (!attr_set) {
    (void)hipFuncSetAttribute((const void*)fused_kernel,
                              hipFuncAttributeMaxDynamicSharedMemorySize, LDS_BYTES);
    attr_set = true;
  }

  setup_kernel<<<64, 256, 0, stream>>>(wq, bq, wk, wvw, Mbf, wvbf, u);
  fused_kernel<<<1024, 512, LDS_BYTES, stream>>>(x, norm_w, norm_b, bvv, beta, Mbf, wvbf, u, out);
}

// Round 7
// 241.310 us; speedup vs baseline: 1.3099x; 1.3099x over previous
//
#include <hip/hip_runtime.h>
#include <hip/hip_bf16.h>

typedef short short8 __attribute__((ext_vector_type(8)));
typedef float f32x4 __attribute__((ext_vector_type(4)));

// LDS arena 81920 B -> 2 blocks/CU.
// [0,64K):  XN bf16 xn^T [w][c]                     (P2->P3)
//           then AT fp8 A[w][v] [0,16K) + XS fp8 x[c][v] [16K,48K)   (post-P3 -> P4)
//           then YT bf16 Y^T [w][c] full 64K         (post-P4 -> P5)
//           then FLD bf16 F packed [0,64K)           (post-P5 -> epilogue)
// [64K,72K) GB (P3 G-band) || overlay NW/NB/UU/MUO/RSO/UDO (P0-P2, dead before GB writes)
// [72K,80K) SUMO/SQO stat partials (P1-P2 only)
#define XN 0
#define AT 0
#define XS 16384
#define YT 0
#define FLD 0
#define GB 65536
#define NW 65536
#define NB 66560
#define UU 67584
#define MUO 68608
#define RSO 69120
#define UDO 69632
#define SUMO 73728
#define SQO 77824
#define LDS_BYTES 81920

__device__ inline unsigned short cvtbf(float f){
  unsigned int x = __float_as_uint(f);
  x += 0x7fffu + ((x >> 16) & 1u);           // RNE
  return (unsigned short)(x >> 16);
}
__device__ inline float bf2f(unsigned short u){ return __uint_as_float(((unsigned int)u) << 16); }
// packed f32x2 -> bf16x2, proven manual RNE (R1-R4/R6; inline-asm cvt_pk NaN'd in R5)
__device__ inline unsigned int pk2(float a, float b){
  return (unsigned int)cvtbf(a) | ((unsigned int)cvtbf(b) << 16);
}
__device__ inline float lo16(unsigned int v){ return bf2f((unsigned short)(v & 0xffffu)); }
__device__ inline float hi16(unsigned int v){ return bf2f((unsigned short)(v >> 16)); }

// setup: M = wq^T wk (bf16), wv -> bf16, u = wk^T bq. 64 blocks x 4 rows each.
__global__ void __launch_bounds__(256) setup_kernel(
    const float* __restrict__ wq, const float* __restrict__ bq,
    const float* __restrict__ wk, const float* __restrict__ wvw,
    unsigned short* __restrict__ Mbf, unsigned short* __restrict__ wvbf, float* __restrict__ u){
  int t = threadIdx.x;
  int c1b = blockIdx.x * 4;
  float acc[4] = {0.f,0.f,0.f,0.f};
  for (int o = 0; o < 256; ++o){
    float wkv = wk[o*256 + t];
    #pragma unroll
    for (int i = 0; i < 4; ++i) acc[i] = fmaf(wq[o*256 + c1b + i], wkv, acc[i]);
  }
  #pragma unroll
  for (int i = 0; i < 4; ++i){
    Mbf[(c1b+i)*256 + t] = cvtbf(acc[i]);
    wvbf[(c1b+i)*256 + t] = cvtbf(wvw[(c1b+i)*256 + t]);
  }
  if (blockIdx.x == 0){
    float a2 = 0.f;
    for (int o = 0; o < 256; ++o) a2 = fmaf(wk[o*256 + t], bq[o], a2);
    u[t] = a2;
  }
}

__global__ void __launch_bounds__(512, 4) fused_kernel(
    const float* __restrict__ x, const float* __restrict__ nw, const float* __restrict__ nbp,
    const float* __restrict__ bvv, const float* __restrict__ beta,
    const unsigned short* __restrict__ Mbf, const unsigned short* __restrict__ wvbf,
    const float* __restrict__ u, float* __restrict__ out){
  extern __shared__ char smem[];
  const int t = threadIdx.x;
  const int lane = t & 63, wv8 = t >> 6;      // 8 waves
  const int g = lane >> 4, li = lane & 15;
  const int b = blockIdx.x >> 7, h = blockIdx.x & 127;
  const size_t base = (size_t)b*4194304 + (size_t)h*128;  // x[b,c,h,w] = base + c*16384 + w

  // ---- P0: stage norm params into LDS (GB-overlay region, dead before P3's GB writes)
  if (t < 256){
    ((float*)(smem + NW))[t] = nw[t];
    ((float*)(smem + NB))[t] = nbp[t];
    ((float*)(smem + UU))[t] = u[t];
  }

  // ---- P1: coalesced float2 x loads (512B/wave), per-w stats; keep x bf16-packed in xp
  // xp dies at the XS-fp8 write (end of P3 region) -- NOT live across P4/P5 (spill fix)
  const int w2 = t & 63, s = t >> 6;          // thread owns c in [s*32,s*32+32), w in {2w2,2w2+1}
  unsigned int xp[32];                         // xp[j] = packed bf16 (x[s*32+j][2w2], x[..][2w2+1])
  {
    const float* xw = x + base + (size_t)(s*32)*16384 + 2*w2;
    float sm0 = 0.f, sq0 = 0.f, sm1 = 0.f, sq1 = 0.f;
    #pragma unroll
    for (int j = 0; j < 32; ++j){
      float2 v = *(const float2*)(xw + (size_t)j*16384);
      sm0 += v.x; sq0 = fmaf(v.x, v.x, sq0);
      sm1 += v.y; sq1 = fmaf(v.y, v.y, sq1);
      xp[j] = pk2(v.x, v.y);
    }
    ((float*)(smem + SUMO))[s*128 + 2*w2]     = sm0;
    ((float*)(smem + SUMO))[s*128 + 2*w2 + 1] = sm1;
    ((float*)(smem + SQO))[s*128 + 2*w2]      = sq0;
    ((float*)(smem + SQO))[s*128 + 2*w2 + 1]  = sq1;
  }
  __syncthreads();
  if (t < 128){
    float sm = 0.f, sq = 0.f;
    #pragma unroll
    for (int q = 0; q < 8; ++q){ sm += ((float*)(smem+SUMO))[q*128+t]; sq += ((float*)(smem+SQO))[q*128+t]; }
    float mu = sm * (1.f/256.f);
    float var = sq * (1.f/256.f) - mu*mu;
    ((float*)(smem+MUO))[t] = mu;
    ((float*)(smem+RSO))[t] = rsqrtf(var + 1e-6f);
  }
  __syncthreads();

  // ---- P2: xn^T [w][c] from registers (2 w-rows per thread); udot partials
  {
    float ud[2] = {0.f, 0.f};
    #pragma unroll
    for (int r = 0; r < 2; ++r){
      int w = 2*w2 + r;
      float mu = ((float*)(smem+MUO))[w], rs = ((float*)(smem+RSO))[w];
      #pragma unroll
      for (int i = 0; i < 4; ++i){
        int c0 = s*32 + i*8;
        unsigned int uu[4];
        #pragma unroll
        for (int j = 0; j < 4; ++j){
          int c = c0 + j*2;
          unsigned int pa = xp[i*8 + j*2];
          unsigned int pb = xp[i*8 + j*2 + 1];
          float x0 = bf2f((unsigned short)(r ? (pa >> 16) : (pa & 0xffffu)));
          float x1 = bf2f((unsigned short)(r ? (pb >> 16) : (pb & 0xffffu)));
          float n0 = (x0 - mu)*rs*((float*)(smem+NW))[c]   + ((float*)(smem+NB))[c];
          float n1 = (x1 - mu)*rs*((float*)(smem+NW))[c+1] + ((float*)(smem+NB))[c+1];
          ud[r] = fmaf(((float*)(smem+UU))[c], n0, fmaf(((float*)(smem+UU))[c+1], n1, ud[r]));
          uu[j] = pk2(n0, n1);
        }
        *(uint4*)(smem + XN + w*512 + ((2*c0) ^ ((w&31)<<4))) = *(const uint4*)uu;
      }
    }
    __syncthreads();   // stat reads of SUMO done; safe to overwrite with ud partials
    ((float*)(smem+SUMO))[s*128 + 2*w2]     = ud[0];
    ((float*)(smem+SUMO))[s*128 + 2*w2 + 1] = ud[1];
  }
  __syncthreads();
  if (t < 128){
    float ud = 0.f;
    #pragma unroll
    for (int q = 0; q < 8; ++q) ud += ((float*)(smem+SUMO))[q*128+t];
    ((float*)(smem+UDO))[t] = ud;
  }
  __syncthreads();

  // ---- P3: S^T[v][w] = sum_o G[o][v]*xn[o][w] (+udot[v]), G in 32-row bands
  f32x4 Sacc[8];
  #pragma unroll
  for (int vt = 0; vt < 8; ++vt){
    int vb = vt*16 + g*4;
    #pragma unroll
    for (int r = 0; r < 4; ++r) Sacc[vt][r] = ((float*)(smem+UDO))[vb + r];
  }
  const int ot = wv8 >> 2, vp = wv8 & 3;
  const int wt = wv8;
  #pragma unroll
  for (int k8 = 0; k8 < 8; ++k8){
    // G band: this wave computes 16 o' x 32 v
    f32x4 Ga[2] = {{0.f,0.f,0.f,0.f},{0.f,0.f,0.f,0.f}};
    const int o = k8*32 + ot*16 + li;
    __builtin_amdgcn_s_setprio(1);
    #pragma unroll
    for (int kk = 0; kk < 8; ++kk){
      short8 afr = *(const short8*)(Mbf + o*256 + kk*32 + g*8);
      #pragma unroll
      for (int j = 0; j < 2; ++j){
        int v = (vp*2 + j)*16 + li;
        short8 bfr = *(const short8*)(smem + XN + v*512 + ((2*(kk*32 + g*8)) ^ ((v&31)<<4)));
        Ga[j] = __builtin_amdgcn_mfma_f32_16x16x32_bf16(afr, bfr, Ga[j], 0, 0, 0);
      }
    }
    __builtin_amdgcn_s_setprio(0);
    __syncthreads();  // prev band's S reads of GB complete
    #pragma unroll
    for (int j = 0; j < 2; ++j){
      int v = (vp*2 + j)*16 + li;
      int ob = ot*16 + g*4;
      uint2 p; p.x = pk2(Ga[j][0], Ga[j][1]); p.y = pk2(Ga[j][2], Ga[j][3]);
      *(uint2*)(smem + GB + v*64 + ((2*ob) ^ ((v&3)<<4))) = p;
    }
    __syncthreads();
    {
      int ww = wt*16 + li;
      short8 bfr = *(const short8*)(smem + XN + ww*512 + ((2*(k8*32 + g*8)) ^ ((ww&31)<<4)));
      __builtin_amdgcn_s_setprio(1);
      #pragma unroll
      for (int vt = 0; vt < 8; ++vt){
        int v = vt*16 + li;
        short8 afr = *(const short8*)(smem + GB + v*64 + ((16*g) ^ ((v&3)<<4)));
        Sacc[vt] = __builtin_amdgcn_mfma_f32_16x16x32_bf16(afr, bfr, Sacc[vt], 0, 0, 0);
      }
      __builtin_amdgcn_s_setprio(0);
    }
  }
  __syncthreads();   // XN fully dead

  // ---- XS: x -> fp8 [c][v] from xp registers (32KB at [16K,48K)); LAST use of xp
  #pragma unroll
  for (int j = 0; j < 32; ++j){
    int c = s*32 + j;
    int pr = __builtin_amdgcn_cvt_pk_fp8_f32(lo16(xp[j]), hi16(xp[j]), 0, false);
    *(unsigned short*)(smem + XS + c*128 + ((2*w2) ^ ((c&15)<<3))) = (unsigned short)pr;
  }

  // ---- softmax over v (rows of S^T), write A as fp8 [w][v] (16KB at [0,16K))
  float mx = -3.4e38f;
  #pragma unroll
  for (int vt = 0; vt < 8; ++vt)
    #pragma unroll
    for (int r = 0; r < 4; ++r){ float sv = Sacc[vt][r]*0.0625f; Sacc[vt][r] = sv; mx = fmaxf(mx, sv); }
  mx = fmaxf(mx, __shfl_xor(mx, 16));
  mx = fmaxf(mx, __shfl_xor(mx, 32));
  float sum = 0.f;
  #pragma unroll
  for (int vt = 0; vt < 8; ++vt)
    #pragma unroll
    for (int r = 0; r < 4; ++r){ float p = exp2f((Sacc[vt][r]-mx)*1.44269504f); Sacc[vt][r] = p; sum += p; }
  sum += __shfl_xor(sum, 16);
  sum += __shfl_xor(sum, 32);
  float inv = 1.f / sum;
  {
    int ww = wt*16 + li;
    #pragma unroll
    for (int vt = 0; vt < 8; ++vt){
      int pr = __builtin_amdgcn_cvt_pk_fp8_f32(Sacc[vt][0]*inv, Sacc[vt][1]*inv, 0, false);
      pr = __builtin_amdgcn_cvt_pk_fp8_f32(Sacc[vt][2]*inv, Sacc[vt][3]*inv, pr, true);
      *(unsigned int*)(smem + AT + ww*128 + ((vt*16 + g*4) ^ ((ww&15)<<3))) = (unsigned int)pr;
    }
  }
  __syncthreads();

  // ---- P4: Y[c][w] = sum_v x[c][v] A[w][v], all-fp8 MFMA from LDS
  f32x4 Yacc[2][8];
  #pragma unroll
  for (int ci = 0; ci < 2; ++ci)
    #pragma unroll
    for (int w2i = 0; w2i < 8; ++w2i) Yacc[ci][w2i] = (f32x4){0.f,0.f,0.f,0.f};
  #pragma unroll
  for (int kk = 0; kk < 4; ++kk){
    long af[2];
    #pragma unroll
    for (int ci = 0; ci < 2; ++ci){
      int c = (wv8*2 + ci)*16 + li;
      af[ci] = *(const long*)(smem + XS + c*128 + ((kk*32 + g*8) ^ ((c&15)<<3)));
    }
    __builtin_amdgcn_s_setprio(1);
    #pragma unroll
    for (int w2i = 0; w2i < 8; ++w2i){
      int ww = w2i*16 + li;
      long bf = *(const long*)(smem + AT + ww*128 + ((kk*32 + g*8) ^ ((ww&15)<<3)));
      #pragma unroll
      for (int ci = 0; ci < 2; ++ci)
        Yacc[ci][w2i] = __builtin_amdgcn_mfma_f32_16x16x32_fp8_fp8(af[ci], bf, Yacc[ci][w2i], 0, 0, 0);
    }
    __builtin_amdgcn_s_setprio(0);
  }
  __syncthreads();   // all P4 reads of XS/AT done; [0,64K) free for YT

  // ---- Y write: full Y^T bf16 [w][c] (64KB); Yacc dies here, before Facc is born
  #pragma unroll
  for (int ci = 0; ci < 2; ++ci){
    int cb = (wv8*2 + ci)*16 + g*4;
    #pragma unroll
    for (int w2i = 0; w2i < 8; ++w2i){
      int ww = w2i*16 + li;
      uint2 p; p.x = pk2(Yacc[ci][w2i][0], Yacc[ci][w2i][1]); p.y = pk2(Yacc[ci][w2i][2], Yacc[ci][w2i][3]);
      *(uint2*)(smem + YT + ww*512 + ((2*cb) ^ ((ww&31)<<4))) = p;
    }
  }
  __syncthreads();

  // ---- P5: F[o][w] = sum_c wv[o][c] Y[c][w], single full-K phase (wv from global/L2)
  f32x4 Facc[2][8];
  #pragma unroll
  for (int oi = 0; oi < 2; ++oi)
    #pragma unroll
    for (int w2i = 0; w2i < 8; ++w2i) Facc[oi][w2i] = (f32x4){0.f,0.f,0.f,0.f};
  #pragma unroll
  for (int kk = 0; kk < 8; ++kk){
    short8 afr[2];
    #pragma unroll
    for (int oi = 0; oi < 2; ++oi){
      int o = (wv8*2 + oi)*16 + li;
      afr[oi] = *(const short8*)(wvbf + o*256 + kk*32 + g*8);
    }
    __builtin_amdgcn_s_setprio(1);
    #pragma unroll
    for (int w2i = 0; w2i < 8; ++w2i){
      int ww = w2i*16 + li;
      short8 bfr = *(const short8*)(smem + YT + ww*512 + ((2*(kk*32 + g*8)) ^ ((ww&31)<<4)));
      #pragma unroll
      for (int oi = 0; oi < 2; ++oi)
        Facc[oi][w2i] = __builtin_amdgcn_mfma_f32_16x16x32_bf16(afr[oi], bfr, Facc[oi][w2i], 0, 0, 0);
    }
    __builtin_amdgcn_s_setprio(0);
  }
  __syncthreads();   // YT dead; [0,64K) free for FLD

  // ---- FLD: Ffin = (F+bv)*beta as bf16, packed (o-pair, w); bv/beta from global (L2-hot)
  #pragma unroll
  for (int oi = 0; oi < 2; ++oi){
    #pragma unroll
    for (int rp = 0; rp < 2; ++rp){
      int o0 = (wv8*2 + oi)*16 + g*4 + 2*rp;   // even o
      int orow = o0 >> 1;
      float2 bv2 = *(const float2*)(bvv + o0);
      float2 bt2 = *(const float2*)(beta + o0);
      #pragma unroll
      for (int w2i = 0; w2i < 8; ++w2i){
        int w = w2i*16 + li;
        float f0 = (Facc[oi][w2i][2*rp]   + bv2.x)*bt2.x;
        float f1 = (Facc[oi][w2i][2*rp+1] + bv2.y)*bt2.y;
        *(unsigned int*)(smem + FLD + orow*512 + ((4*w) ^ ((orow&7)<<4))) = pk2(f0, f1);
      }
    }
  }
  __syncthreads();

  // ---- epilogue: out = x(re-read f32, coalesced) + Ffin; coalesced float2 stores
  #pragma unroll
  for (int j = 0; j < 16; ++j){
    int crow = s*16 + j;                        // = (s*32+2j)>>1
    uint2 u2 = *(const uint2*)(smem + FLD + crow*512 + ((8*w2) ^ ((crow&7)<<4)));
    size_t c0 = (size_t)(s*32 + 2*j);
    const float2 xa = *(const float2*)(x + base + c0*16384 + 2*w2);
    const float2 xb = *(const float2*)(x + base + (c0+1)*16384 + 2*w2);
    float2 o0, o1;
    o0.x = xa.x + lo16(u2.x);
    o0.y = xa.y + lo16(u2.y);
    o1.x = xb.x + hi16(u2.x);
    o1.y = xb.y + hi16(u2.y);
    *(float2*)(out + base + c0*16384 + 2*w2)       = o0;
    *(float2*)(out + base + (c0+1)*16384 + 2*w2)   = o1;
  }
}

extern "C" void kernel_launch(void* const* d_in, const int* in_sizes, int n_in,
                              void* d_out, int out_size, void* d_ws, size_t ws_size,
                              hipStream_t stream) {
  (void)in_sizes; (void)n_in; (void)out_size; (void)ws_size;
  const float* x      = (const float*)d_in[0];
  const float* norm_w = (const float*)d_in[1];
  const float* norm_b = (const float*)d_in[2];
  const float* wq     = (const float*)d_in[3];
  const float* bq     = (const float*)d_in[4];
  const float* wk     = (const float*)d_in[5];
  // d_in[6] = bk: only enters softmax-invariant terms, mathematically dropped
  const float* wvw    = (const float*)d_in[7];
  const float* bvv    = (const float*)d_in[8];
  const float* beta   = (const float*)d_in[9];
  float* out = (float*)d_out;

  unsigned short* Mbf  = (unsigned short*)d_ws;                    // 128 KB
  unsigned short* wvbf = (unsigned short*)((char*)d_ws + 131072);  // 128 KB
  float* u             = (float*)((char*)d_ws + 262144);           // 1 KB

  static bool attr_set = false;
  if (!attr_set) {
    (void)hipFuncSetAttribute((const void*)fused_kernel,
                              hipFuncAttributeMaxDynamicSharedMemorySize, LDS_BYTES);
    attr_set = true;
  }

  setup_kernel<<<64, 256, 0, stream>>>(wq, bq, wk, wvw, Mbf, wvbf, u);
  fused_kernel<<<1024, 512, LDS_BYTES, stream>>>(x, norm_w, norm_b, bvv, beta, Mbf, wvbf, u, out);
}

// Round 8
// 225.753 us; speedup vs baseline: 1.4002x; 1.0689x over previous
//
#include <hip/hip_runtime.h>
#include <hip/hip_bf16.h>

typedef short short8 __attribute__((ext_vector_type(8)));
typedef float f32x4 __attribute__((ext_vector_type(4)));

// LDS arena 81920 B -> 2 blocks/CU.
// [0,64K):  XN bf16 xn^T [w][c]                     (P2->P3)
//           then AT fp8 A[w][v] [0,16K) + XS fp8 x[c][v] [16K,48K)   (post-P3 -> P4)
//           then YT bf16 Y^T [w][c] full 64K         (post-P4 -> P5)
//           then FLD bf16 F packed [0,64K)           (post-P5 -> epilogue)
// [64K,72K) GB (P3 G-band) || overlay NW/NB/UU/MUO/RSO/UDO (P0-P2, dead before GB writes)
// [72K,80K) SUMO/SQO stat partials (P1-P2 only)
#define XN 0
#define AT 0
#define XS 16384
#define YT 0
#define FLD 0
#define GB 65536
#define NW 65536
#define NB 66560
#define UU 67584
#define MUO 68608
#define RSO 69120
#define UDO 69632
#define SUMO 73728
#define SQO 77824
#define LDS_BYTES 81920

__device__ inline unsigned short cvtbf(float f){
  unsigned int x = __float_as_uint(f);
  x += 0x7fffu + ((x >> 16) & 1u);           // RNE
  return (unsigned short)(x >> 16);
}
__device__ inline float bf2f(unsigned short u){ return __uint_as_float(((unsigned int)u) << 16); }
// packed f32x2 -> bf16x2, proven manual RNE (R1-R4/R6/R7; inline-asm cvt_pk NaN'd in R5)
__device__ inline unsigned int pk2(float a, float b){
  return (unsigned int)cvtbf(a) | ((unsigned int)cvtbf(b) << 16);
}
__device__ inline float lo16(unsigned int v){ return bf2f((unsigned short)(v & 0xffffu)); }
__device__ inline float hi16(unsigned int v){ return bf2f((unsigned short)(v >> 16)); }

// setup: M = wq^T wk (bf16), wv -> bf16, u = wk^T bq. 64 blocks x 4 rows each.
__global__ void __launch_bounds__(256) setup_kernel(
    const float* __restrict__ wq, const float* __restrict__ bq,
    const float* __restrict__ wk, const float* __restrict__ wvw,
    unsigned short* __restrict__ Mbf, unsigned short* __restrict__ wvbf, float* __restrict__ u){
  int t = threadIdx.x;
  int c1b = blockIdx.x * 4;
  float acc[4] = {0.f,0.f,0.f,0.f};
  for (int o = 0; o < 256; ++o){
    float wkv = wk[o*256 + t];
    #pragma unroll
    for (int i = 0; i < 4; ++i) acc[i] = fmaf(wq[o*256 + c1b + i], wkv, acc[i]);
  }
  #pragma unroll
  for (int i = 0; i < 4; ++i){
    Mbf[(c1b+i)*256 + t] = cvtbf(acc[i]);
    wvbf[(c1b+i)*256 + t] = cvtbf(wvw[(c1b+i)*256 + t]);
  }
  if (blockIdx.x == 0){
    float a2 = 0.f;
    for (int o = 0; o < 256; ++o) a2 = fmaf(wk[o*256 + t], bq[o], a2);
    u[t] = a2;
  }
}

__global__ void __launch_bounds__(512, 4) fused_kernel(
    const float* __restrict__ x, const float* __restrict__ nw, const float* __restrict__ nbp,
    const float* __restrict__ bvv, const float* __restrict__ beta,
    const unsigned short* __restrict__ Mbf, const unsigned short* __restrict__ wvbf,
    const float* __restrict__ u, float* __restrict__ out){
  extern __shared__ char smem[];
  const int t = threadIdx.x;
  const int lane = t & 63, wv8 = t >> 6;      // 8 waves
  const int g = lane >> 4, li = lane & 15;
  const int b = blockIdx.x >> 7, h = blockIdx.x & 127;
  const size_t base = (size_t)b*4194304 + (size_t)h*128;  // x[b,c,h,w] = base + c*16384 + w

  // ---- P0: stage norm params into LDS (GB-overlay region, dead before P3's GB writes)
  if (t < 256){
    ((float*)(smem + NW))[t] = nw[t];
    ((float*)(smem + NB))[t] = nbp[t];
    ((float*)(smem + UU))[t] = u[t];
  }

  // ---- P1: 16x float4 loads, 2 batches of 8 issued with NO dependent math between
  // (deep in-flight queue -> HBM-rate). Thread owns c in [sh*16,sh*16+16), w in [wq,wq+4).
  const int w4 = t & 31, sh = t >> 5;
  const int wq = 4*w4;
  unsigned int xp[32];    // xp[2j]=(bf16 x[c][wq],x[c][wq+1]) xp[2j+1]=(wq+2,wq+3), c=16sh+j
  {
    const float* xw = x + base + (size_t)(sh*16)*16384 + wq;
    float4 xa[8], xb[8];
    #pragma unroll
    for (int j = 0; j < 8; ++j) xa[j] = *(const float4*)(xw + (size_t)j*16384);
    #pragma unroll
    for (int j = 0; j < 8; ++j) xb[j] = *(const float4*)(xw + (size_t)(8+j)*16384);
    float sm[4] = {0,0,0,0}, sq[4] = {0,0,0,0};
    #pragma unroll
    for (int j = 0; j < 8; ++j){
      sm[0]+=xa[j].x; sq[0]=fmaf(xa[j].x,xa[j].x,sq[0]);
      sm[1]+=xa[j].y; sq[1]=fmaf(xa[j].y,xa[j].y,sq[1]);
      sm[2]+=xa[j].z; sq[2]=fmaf(xa[j].z,xa[j].z,sq[2]);
      sm[3]+=xa[j].w; sq[3]=fmaf(xa[j].w,xa[j].w,sq[3]);
      xp[2*j]   = pk2(xa[j].x, xa[j].y);
      xp[2*j+1] = pk2(xa[j].z, xa[j].w);
    }
    #pragma unroll
    for (int j = 0; j < 8; ++j){
      sm[0]+=xb[j].x; sq[0]=fmaf(xb[j].x,xb[j].x,sq[0]);
      sm[1]+=xb[j].y; sq[1]=fmaf(xb[j].y,xb[j].y,sq[1]);
      sm[2]+=xb[j].z; sq[2]=fmaf(xb[j].z,xb[j].z,sq[2]);
      sm[3]+=xb[j].w; sq[3]=fmaf(xb[j].w,xb[j].w,sq[3]);
      xp[16+2*j]   = pk2(xb[j].x, xb[j].y);
      xp[16+2*j+1] = pk2(xb[j].z, xb[j].w);
    }
    // lanes l and l^32 hold the two 16-c halves of this wave's 32-c chunk (same w-quad)
    #pragma unroll
    for (int k = 0; k < 4; ++k){
      sm[k] += __shfl_xor(sm[k], 32);
      sq[k] += __shfl_xor(sq[k], 32);
    }
    if (lane < 32){
      #pragma unroll
      for (int k = 0; k < 4; ++k){
        ((float*)(smem + SUMO))[wv8*128 + wq + k] = sm[k];
        ((float*)(smem + SQO ))[wv8*128 + wq + k] = sq[k];
      }
    }
  }
  __syncthreads();
  if (t < 128){
    float sm = 0.f, sq = 0.f;
    #pragma unroll
    for (int q = 0; q < 8; ++q){ sm += ((float*)(smem+SUMO))[q*128+t]; sq += ((float*)(smem+SQO))[q*128+t]; }
    float mu = sm * (1.f/256.f);
    float var = sq * (1.f/256.f) - mu*mu;
    ((float*)(smem+MUO))[t] = mu;
    ((float*)(smem+RSO))[t] = rsqrtf(var + 1e-6f);
  }
  __syncthreads();

  // ---- P2: xn^T [w][c] from registers (4 w-rows x 16 c per thread); udot partials
  {
    float mu4[4], rs4[4];
    #pragma unroll
    for (int k = 0; k < 4; ++k){
      mu4[k] = ((float*)(smem+MUO))[wq+k];
      rs4[k] = ((float*)(smem+RSO))[wq+k];
    }
    float ud4[4] = {0,0,0,0};
    unsigned int npk[4][8];   // npk[k][jp] = bf16 pair (xn[c0][wq+k], xn[c0+1][wq+k])
    #pragma unroll
    for (int jp = 0; jp < 8; ++jp){
      int c0 = sh*16 + 2*jp;
      float nw0 = ((float*)(smem+NW))[c0],   nb0 = ((float*)(smem+NB))[c0],   u0 = ((float*)(smem+UU))[c0];
      float nw1 = ((float*)(smem+NW))[c0+1], nb1 = ((float*)(smem+NB))[c0+1], u1 = ((float*)(smem+UU))[c0+1];
      unsigned int pa0 = xp[4*jp],   pa1 = xp[4*jp+1];
      unsigned int pb0 = xp[4*jp+2], pb1 = xp[4*jp+3];
      float x0[4] = { lo16(pa0), hi16(pa0), lo16(pa1), hi16(pa1) };
      float x1[4] = { lo16(pb0), hi16(pb0), lo16(pb1), hi16(pb1) };
      #pragma unroll
      for (int k = 0; k < 4; ++k){
        float n0 = (x0[k] - mu4[k])*rs4[k]*nw0 + nb0;
        float n1 = (x1[k] - mu4[k])*rs4[k]*nw1 + nb1;
        ud4[k] = fmaf(u0, n0, fmaf(u1, n1, ud4[k]));
        npk[k][jp] = pk2(n0, n1);
      }
    }
    #pragma unroll
    for (int k = 0; k < 4; ++k){
      int w = wq + k;
      uint4 lo4; lo4.x = npk[k][0]; lo4.y = npk[k][1]; lo4.z = npk[k][2]; lo4.w = npk[k][3];
      uint4 hi4; hi4.x = npk[k][4]; hi4.y = npk[k][5]; hi4.z = npk[k][6]; hi4.w = npk[k][7];
      *(uint4*)(smem + XN + w*512 + ((32*sh)      ^ ((w&31)<<4))) = lo4;
      *(uint4*)(smem + XN + w*512 + ((32*sh + 16) ^ ((w&31)<<4))) = hi4;
    }
    #pragma unroll
    for (int k = 0; k < 4; ++k) ud4[k] += __shfl_xor(ud4[k], 32);
    __syncthreads();   // stat reads of SUMO done; safe to overwrite with ud partials
    if (lane < 32){
      #pragma unroll
      for (int k = 0; k < 4; ++k)
        ((float*)(smem+SUMO))[wv8*128 + wq + k] = ud4[k];
    }
  }
  __syncthreads();
  if (t < 128){
    float ud = 0.f;
    #pragma unroll
    for (int q = 0; q < 8; ++q) ud += ((float*)(smem+SUMO))[q*128+t];
    ((float*)(smem+UDO))[t] = ud;
  }
  __syncthreads();

  // ---- P3: S^T[v][w] = sum_o G[o][v]*xn[o][w] (+udot[v]), G in 32-row bands
  f32x4 Sacc[8];
  #pragma unroll
  for (int vt = 0; vt < 8; ++vt){
    int vb = vt*16 + g*4;
    #pragma unroll
    for (int r = 0; r < 4; ++r) Sacc[vt][r] = ((float*)(smem+UDO))[vb + r];
  }
  const int ot = wv8 >> 2, vp = wv8 & 3;
  const int wt = wv8;
  #pragma unroll
  for (int k8 = 0; k8 < 8; ++k8){
    // G band: this wave computes 16 o' x 32 v
    f32x4 Ga[2] = {{0.f,0.f,0.f,0.f},{0.f,0.f,0.f,0.f}};
    const int o = k8*32 + ot*16 + li;
    __builtin_amdgcn_s_setprio(1);
    #pragma unroll
    for (int kk = 0; kk < 8; ++kk){
      short8 afr = *(const short8*)(Mbf + o*256 + kk*32 + g*8);
      #pragma unroll
      for (int j = 0; j < 2; ++j){
        int v = (vp*2 + j)*16 + li;
        short8 bfr = *(const short8*)(smem + XN + v*512 + ((2*(kk*32 + g*8)) ^ ((v&31)<<4)));
        Ga[j] = __builtin_amdgcn_mfma_f32_16x16x32_bf16(afr, bfr, Ga[j], 0, 0, 0);
      }
    }
    __builtin_amdgcn_s_setprio(0);
    __syncthreads();  // prev band's S reads of GB complete
    #pragma unroll
    for (int j = 0; j < 2; ++j){
      int v = (vp*2 + j)*16 + li;
      int ob = ot*16 + g*4;
      uint2 p; p.x = pk2(Ga[j][0], Ga[j][1]); p.y = pk2(Ga[j][2], Ga[j][3]);
      *(uint2*)(smem + GB + v*64 + ((2*ob) ^ ((v&3)<<4))) = p;
    }
    __syncthreads();
    {
      int ww = wt*16 + li;
      short8 bfr = *(const short8*)(smem + XN + ww*512 + ((2*(k8*32 + g*8)) ^ ((ww&31)<<4)));
      __builtin_amdgcn_s_setprio(1);
      #pragma unroll
      for (int vt = 0; vt < 8; ++vt){
        int v = vt*16 + li;
        short8 afr = *(const short8*)(smem + GB + v*64 + ((16*g) ^ ((v&3)<<4)));
        Sacc[vt] = __builtin_amdgcn_mfma_f32_16x16x32_bf16(afr, bfr, Sacc[vt], 0, 0, 0);
      }
      __builtin_amdgcn_s_setprio(0);
    }
  }
  __syncthreads();   // XN fully dead

  // ---- XS: x -> fp8 [c][v] from xp registers (32KB at [16K,48K)); LAST use of xp
  #pragma unroll
  for (int j = 0; j < 16; ++j){
    int c = sh*16 + j;
    int pr = __builtin_amdgcn_cvt_pk_fp8_f32(lo16(xp[2*j]),   hi16(xp[2*j]),   0,  false);
    pr     = __builtin_amdgcn_cvt_pk_fp8_f32(lo16(xp[2*j+1]), hi16(xp[2*j+1]), pr, true);
    *(unsigned int*)(smem + XS + c*128 + (wq ^ ((c&15)<<3))) = (unsigned int)pr;
  }

  // ---- softmax over v (rows of S^T), write A as fp8 [w][v] (16KB at [0,16K))
  float mx = -3.4e38f;
  #pragma unroll
  for (int vt = 0; vt < 8; ++vt)
    #pragma unroll
    for (int r = 0; r < 4; ++r){ float sv = Sacc[vt][r]*0.0625f; Sacc[vt][r] = sv; mx = fmaxf(mx, sv); }
  mx = fmaxf(mx, __shfl_xor(mx, 16));
  mx = fmaxf(mx, __shfl_xor(mx, 32));
  float sum = 0.f;
  #pragma unroll
  for (int vt = 0; vt < 8; ++vt)
    #pragma unroll
    for (int r = 0; r < 4; ++r){ float p = exp2f((Sacc[vt][r]-mx)*1.44269504f); Sacc[vt][r] = p; sum += p; }
  sum += __shfl_xor(sum, 16);
  sum += __shfl_xor(sum, 32);
  float inv = 1.f / sum;
  {
    int ww = wt*16 + li;
    #pragma unroll
    for (int vt = 0; vt < 8; ++vt){
      int pr = __builtin_amdgcn_cvt_pk_fp8_f32(Sacc[vt][0]*inv, Sacc[vt][1]*inv, 0, false);
      pr = __builtin_amdgcn_cvt_pk_fp8_f32(Sacc[vt][2]*inv, Sacc[vt][3]*inv, pr, true);
      *(unsigned int*)(smem + AT + ww*128 + ((vt*16 + g*4) ^ ((ww&15)<<3))) = (unsigned int)pr;
    }
  }
  __syncthreads();

  // ---- P4: Y[c][w] = sum_v x[c][v] A[w][v], all-fp8 MFMA from LDS
  f32x4 Yacc[2][8];
  #pragma unroll
  for (int ci = 0; ci < 2; ++ci)
    #pragma unroll
    for (int w2i = 0; w2i < 8; ++w2i) Yacc[ci][w2i] = (f32x4){0.f,0.f,0.f,0.f};
  #pragma unroll
  for (int kk = 0; kk < 4; ++kk){
    long af[2];
    #pragma unroll
    for (int ci = 0; ci < 2; ++ci){
      int c = (wv8*2 + ci)*16 + li;
      af[ci] = *(const long*)(smem + XS + c*128 + ((kk*32 + g*8) ^ ((c&15)<<3)));
    }
    __builtin_amdgcn_s_setprio(1);
    #pragma unroll
    for (int w2i = 0; w2i < 8; ++w2i){
      int ww = w2i*16 + li;
      long bf = *(const long*)(smem + AT + ww*128 + ((kk*32 + g*8) ^ ((ww&15)<<3)));
      #pragma unroll
      for (int ci = 0; ci < 2; ++ci)
        Yacc[ci][w2i] = __builtin_amdgcn_mfma_f32_16x16x32_fp8_fp8(af[ci], bf, Yacc[ci][w2i], 0, 0, 0);
    }
    __builtin_amdgcn_s_setprio(0);
  }
  __syncthreads();   // all P4 reads of XS/AT done; [0,64K) free for YT

  // ---- Y write: full Y^T bf16 [w][c] (64KB); Yacc dies here, before Facc is born
  #pragma unroll
  for (int ci = 0; ci < 2; ++ci){
    int cb = (wv8*2 + ci)*16 + g*4;
    #pragma unroll
    for (int w2i = 0; w2i < 8; ++w2i){
      int ww = w2i*16 + li;
      uint2 p; p.x = pk2(Yacc[ci][w2i][0], Yacc[ci][w2i][1]); p.y = pk2(Yacc[ci][w2i][2], Yacc[ci][w2i][3]);
      *(uint2*)(smem + YT + ww*512 + ((2*cb) ^ ((ww&31)<<4))) = p;
    }
  }
  __syncthreads();

  // ---- P5: F[o][w] = sum_c wv[o][c] Y[c][w], single full-K phase (wv from global/L2)
  f32x4 Facc[2][8];
  #pragma unroll
  for (int oi = 0; oi < 2; ++oi)
    #pragma unroll
    for (int w2i = 0; w2i < 8; ++w2i) Facc[oi][w2i] = (f32x4){0.f,0.f,0.f,0.f};
  #pragma unroll
  for (int kk = 0; kk < 8; ++kk){
    short8 afr[2];
    #pragma unroll
    for (int oi = 0; oi < 2; ++oi){
      int o = (wv8*2 + oi)*16 + li;
      afr[oi] = *(const short8*)(wvbf + o*256 + kk*32 + g*8);
    }
    __builtin_amdgcn_s_setprio(1);
    #pragma unroll
    for (int w2i = 0; w2i < 8; ++w2i){
      int ww = w2i*16 + li;
      short8 bfr = *(const short8*)(smem + YT + ww*512 + ((2*(kk*32 + g*8)) ^ ((ww&31)<<4)));
      #pragma unroll
      for (int oi = 0; oi < 2; ++oi)
        Facc[oi][w2i] = __builtin_amdgcn_mfma_f32_16x16x32_bf16(afr[oi], bfr, Facc[oi][w2i], 0, 0, 0);
    }
    __builtin_amdgcn_s_setprio(0);
  }
  __syncthreads();   // YT dead; [0,64K) free for FLD

  // ---- issue first half of epilogue x re-read NOW (T14: FLD write+barrier hides latency)
  const float* xr = x + base + (size_t)(sh*16)*16384 + wq;
  float* outr = out + base + (size_t)(sh*16)*16384 + wq;
  float4 xa[8];
  #pragma unroll
  for (int j = 0; j < 8; ++j) xa[j] = *(const float4*)(xr + (size_t)j*16384);

  // ---- FLD: Ffin = (F+bv)*beta as bf16, packed (o-pair, w); bv/beta from global (L2-hot)
  #pragma unroll
  for (int oi = 0; oi < 2; ++oi){
    #pragma unroll
    for (int rp = 0; rp < 2; ++rp){
      int o0 = (wv8*2 + oi)*16 + g*4 + 2*rp;   // even o
      int orow = o0 >> 1;
      float2 bv2 = *(const float2*)(bvv + o0);
      float2 bt2 = *(const float2*)(beta + o0);
      #pragma unroll
      for (int w2i = 0; w2i < 8; ++w2i){
        int w = w2i*16 + li;
        float f0 = (Facc[oi][w2i][2*rp]   + bv2.x)*bt2.x;
        float f1 = (Facc[oi][w2i][2*rp+1] + bv2.y)*bt2.y;
        *(unsigned int*)(smem + FLD + orow*512 + ((4*w) ^ ((orow&7)<<4))) = pk2(f0, f1);
      }
    }
  }
  __syncthreads();

  // ---- epilogue: out = x + Ffin; float4 loads/stores, 2nd batch issued before FLD reads
  {
    float4 xb[8];
    #pragma unroll
    for (int j = 0; j < 8; ++j) xb[j] = *(const float4*)(xr + (size_t)(8+j)*16384);
    #pragma unroll
    for (int j2 = 0; j2 < 8; ++j2){
      int orow = sh*8 + j2;
      uint4 fl = *(const uint4*)(smem + FLD + orow*512 + ((16*w4) ^ ((orow&7)<<4)));
      float4 e = (j2 < 4) ? xa[2*j2]     : xb[2*j2-8];
      float4 f = (j2 < 4) ? xa[2*j2+1]   : xb[2*j2-7];
      float4 o0, o1;
      o0.x = e.x + lo16(fl.x); o0.y = e.y + lo16(fl.y); o0.z = e.z + lo16(fl.z); o0.w = e.w + lo16(fl.w);
      o1.x = f.x + hi16(fl.x); o1.y = f.y + hi16(fl.y); o1.z = f.z + hi16(fl.z); o1.w = f.w + hi16(fl.w);
      *(float4*)(outr + (size_t)(2*j2)*16384)   = o0;
      *(float4*)(outr + (size_t)(2*j2+1)*16384) = o1;
    }
  }
}

extern "C" void kernel_launch(void* const* d_in, const int* in_sizes, int n_in,
                              void* d_out, int out_size, void* d_ws, size_t ws_size,
                              hipStream_t stream) {
  (void)in_sizes; (void)n_in; (void)out_size; (void)ws_size;
  const float* x      = (const float*)d_in[0];
  const float* norm_w = (const float*)d_in[1];
  const float* norm_b = (const float*)d_in[2];
  const float* wq     = (const float*)d_in[3];
  const float* bq     = (const float*)d_in[4];
  const float* wk     = (const float*)d_in[5];
  // d_in[6] = bk: only enters softmax-invariant terms, mathematically dropped
  const float* wvw    = (const float*)d_in[7];
  const float* bvv    = (const float*)d_in[8];
  const float* beta   = (const float*)d_in[9];
  float* out = (float*)d_out;

  unsigned short* Mbf  = (unsigned short*)d_ws;                    // 128 KB
  unsigned short* wvbf = (unsigned short*)((char*)d_ws + 131072);  // 128 KB
  float* u             = (float*)((char*)d_ws + 262144);           // 1 KB

  static bool attr_set = false;
  if (!attr_set) {
    (void)hipFuncSetAttribute((const void*)fused_kernel,
                              hipFuncAttributeMaxDynamicSharedMemorySize, LDS_BYTES);
    attr_set = true;
  }

  setup_kernel<<<64, 256, 0, stream>>>(wq, bq, wk, wvw, Mbf, wvbf, u);
  fused_kernel<<<1024, 512, LDS_BYTES, stream>>>(x, norm_w, norm_b, bvv, beta, Mbf, wvbf, u, out);
}